// Round 4
// baseline (656.381 us; speedup 1.0000x reference)
//
#include <hip/hip_runtime.h>
#include <hip/hip_bf16.h>
#include <stdint.h>

// GCNAE: N nodes, E edges, IN features, H hidden.
// Inputs: fp32 storage (bf16-rounded values). Output buffer: fp32
// (adj [N,N] then z [N,H] concatenated flat).
#define N_NODES 10000
#define N_EDGES 320000
#define DIM_IN  128
#define DIM_H   64

typedef __attribute__((ext_vector_type(8))) short  short8;   // 8 bf16 (MFMA A/B frag)
typedef __attribute__((ext_vector_type(4))) float  f32x4;    // MFMA C/D frag

__device__ __forceinline__ unsigned short f2bf(float f) {
    union { float f; unsigned int i; } v; v.f = f;
    unsigned int u = v.i;
    return (unsigned short)((u + 0x7fffu + ((u >> 16) & 1u)) >> 16);  // RNE
}

// ---- 1. histogram of in-degrees -------------------------------------------
__global__ void hist_kernel(const int* __restrict__ ei, int* __restrict__ deg) {
    int e = blockIdx.x * blockDim.x + threadIdx.x;
    if (e < N_EDGES) atomicAdd(&deg[ei[N_EDGES + e]], 1);   // row 1 = dst
}

// ---- 2. exclusive scan (single block, 1024 threads, 10 elems/thread) ------
__global__ void __launch_bounds__(1024) scan_kernel(const int* __restrict__ deg,
                                                    int* __restrict__ offs,
                                                    int* __restrict__ cursor) {
    __shared__ int part[1024];
    int t = threadIdx.x;
    int base = t * 10;
    int local[10];
    int s = 0;
    for (int i = 0; i < 10; ++i) {
        int idx = base + i;
        int d = (idx < N_NODES) ? deg[idx] : 0;
        local[i] = d; s += d;
    }
    part[t] = s;
    __syncthreads();
    for (int o = 1; o < 1024; o <<= 1) {
        int add = (t >= o) ? part[t - o] : 0;
        __syncthreads();
        part[t] += add;
        __syncthreads();
    }
    int run = part[t] - s;          // exclusive prefix for this chunk
    for (int i = 0; i < 10; ++i) {
        int idx = base + i;
        if (idx < N_NODES) { offs[idx] = run; cursor[idx] = run; run += local[i]; }
    }
    if (t == 1023) offs[N_NODES] = part[1023];
}

// ---- 3. bucket edge ids into CSR ------------------------------------------
__global__ void bucket_kernel(const int* __restrict__ ei, int* __restrict__ cursor,
                              int* __restrict__ esorted) {
    int e = blockIdx.x * blockDim.x + threadIdx.x;
    if (e < N_EDGES) {
        int d = ei[N_EDGES + e];
        int slot = atomicAdd(&cursor[d], 1);
        esorted[slot] = e;
    }
}

// ---- 4. per-node aggregate + fused dense: z = agg@W_rel + x@W_root + b ----
// one wave per node; fp32 throughout; writes fp32 z to d_out tail at slot N*N
__global__ void __launch_bounds__(64) agg_dense_kernel(
    const float* __restrict__ x,
    const int* __restrict__ ei,
    const float* __restrict__ ew,
    const float* __restrict__ wrel,
    const float* __restrict__ wroot,
    const float* __restrict__ bias,
    const int* __restrict__ offs,
    const int* __restrict__ esorted,
    float* __restrict__ out)               // d_out (fp32)
{
    int i = blockIdx.x;
    int lane = threadIdx.x;
    __shared__ float aggL[DIM_IN];
    __shared__ float xL[DIM_IN];

    int beg = offs[i], end = offs[i + 1];
    const float2* xrow_i = (const float2*)(x + (size_t)i * DIM_IN);
    float2 xi = xrow_i[lane];              // lane's 2 features of x_i
    float a0 = 0.f, a1 = 0.f;
    for (int p = beg; p < end; ++p) {
        int e = esorted[p];
        int s = ei[e];                     // row 0 = src
        float w = ew[e];
        float2 xv = ((const float2*)(x + (size_t)s * DIM_IN))[lane];
        a0 += w * xv.x;
        a1 += w * xv.y;
    }
    aggL[2 * lane]     = a0;
    aggL[2 * lane + 1] = a1;
    xL[2 * lane]       = xi.x;
    xL[2 * lane + 1]   = xi.y;
    __syncthreads();

    int h = lane;                          // lane -> output feature
    float acc = bias[h];
    for (int k = 0; k < DIM_IN; ++k) {
        acc += aggL[k] * wrel[k * DIM_H + h];    // coalesced along h
        acc += xL[k]   * wroot[k * DIM_H + h];
    }
    out[(size_t)N_NODES * N_NODES + (size_t)i * DIM_H + h] = acc;  // fp32 z
}

// ---- 5. adj = sigmoid(z @ z^T), MFMA bf16, wave tile 32x32, block 64x64 ---
// reads fp32 z from d_out tail (converts to bf16 frags in-register),
// overwrites adj region [0, N*N) — including the CSR scratch at its front.
// adj is symmetric (z z^T), so MFMA row/col orientation cannot break it.
__global__ void __launch_bounds__(256) gemm_sig_kernel(float* __restrict__ out)
{
    const float* zf = out + (size_t)N_NODES * N_NODES;
    int lane = threadIdx.x & 63;
    int wave = threadIdx.x >> 6;
    int wm = wave >> 1, wn = wave & 1;
    int i0 = blockIdx.x * 64 + wm * 32;
    int j0 = blockIdx.y * 64 + wn * 32;
    int l15  = lane & 15;
    int quad = lane >> 4;

    f32x4 acc[2][2];
    for (int a = 0; a < 2; ++a)
        for (int b = 0; b < 2; ++b) acc[a][b] = (f32x4)0.f;

    int rA[2], rB[2];
    for (int mi = 0; mi < 2; ++mi) {
        int r = i0 + mi * 16 + l15; rA[mi] = (r < N_NODES) ? r : (N_NODES - 1);
    }
    for (int ni = 0; ni < 2; ++ni) {
        int r = j0 + ni * 16 + l15; rB[ni] = (r < N_NODES) ? r : (N_NODES - 1);
    }

    for (int s = 0; s < 2; ++s) {                 // K=64 in two K=32 steps
        int kb = s * 32 + quad * 8;               // A[m=lane&15][k=quad*8+j]
        short8 af[2], bfr[2];
        for (int mi = 0; mi < 2; ++mi) {
            const float* p = zf + (size_t)rA[mi] * DIM_H + kb;
            short8 t;
            #pragma unroll
            for (int j = 0; j < 8; ++j) t[j] = (short)f2bf(p[j]);
            af[mi] = t;
        }
        for (int ni = 0; ni < 2; ++ni) {
            const float* p = zf + (size_t)rB[ni] * DIM_H + kb;
            short8 t;
            #pragma unroll
            for (int j = 0; j < 8; ++j) t[j] = (short)f2bf(p[j]);
            bfr[ni] = t;
        }
        for (int mi = 0; mi < 2; ++mi)
            for (int ni = 0; ni < 2; ++ni)
                acc[mi][ni] = __builtin_amdgcn_mfma_f32_16x16x32_bf16(
                    af[mi], bfr[ni], acc[mi][ni], 0, 0, 0);
    }

    // C/D: col = lane&15, row = quad*4 + reg
    for (int mi = 0; mi < 2; ++mi) {
        for (int ni = 0; ni < 2; ++ni) {
            int col = j0 + ni * 16 + l15;
            for (int r = 0; r < 4; ++r) {
                int row = i0 + mi * 16 + quad * 4 + r;
                if (row < N_NODES && col < N_NODES) {
                    float v  = acc[mi][ni][r];
                    float sg = 1.0f / (1.0f + __expf(-v));
                    out[(size_t)row * N_NODES + col] = sg;   // fp32 store
                }
            }
        }
    }
}

extern "C" void kernel_launch(void* const* d_in, const int* in_sizes, int n_in,
                              void* d_out, int out_size, void* d_ws, size_t ws_size,
                              hipStream_t stream) {
    const float* x     = (const float*)d_in[0];  // [N,128] fp32
    const int*   ei    = (const int*)d_in[1];    // [2,E] int32
    const float* ew    = (const float*)d_in[2];  // [E] fp32
    const float* wrel  = (const float*)d_in[3];  // [128,64] fp32
    const float* wroot = (const float*)d_in[4];  // [128,64] fp32
    const float* bias  = (const float*)d_in[5];  // [64] fp32
    float* out = (float*)d_out;                  // fp32: adj [N*N] then z [N*64]

    // CSR scratch lives at the FRONT of the fp32 adj region (first ~1.4 MB of
    // 400 MB) and is fully overwritten by gemm_sig afterwards. d_ws unused.
    char* base = (char*)d_out;
    int* esorted = (int*)(base);                 // E ints   [0, 1,280,000)
    int* deg     = (int*)(base + 1280000);       // N ints
    int* offs    = (int*)(base + 1320000);       // N+1 ints
    int* cursor  = (int*)(base + 1360004);       // N ints

    hipMemsetAsync(deg, 0, N_NODES * sizeof(int), stream);
    hist_kernel<<<(N_EDGES + 255) / 256, 256, 0, stream>>>(ei, deg);
    scan_kernel<<<1, 1024, 0, stream>>>(deg, offs, cursor);
    bucket_kernel<<<(N_EDGES + 255) / 256, 256, 0, stream>>>(ei, cursor, esorted);
    agg_dense_kernel<<<N_NODES, 64, 0, stream>>>(x, ei, ew, wrel, wroot, bias,
                                                 offs, esorted, out);
    dim3 grid((N_NODES + 63) / 64, (N_NODES + 63) / 64);
    gemm_sig_kernel<<<grid, 256, 0, stream>>>(out);
}

// Round 5
// 569.471 us; speedup vs baseline: 1.1526x; 1.1526x over previous
//
#include <hip/hip_runtime.h>
#include <hip/hip_bf16.h>
#include <stdint.h>

// GCNAE: N nodes, E edges, IN features, H hidden.
// Inputs fp32 (bf16-rounded values). Output fp32: adj [N,N] then z [N,H].
#define N_NODES 10000
#define N_EDGES 320000
#define DIM_IN  128
#define DIM_H   64
#define SSTR    72     // LDS row stride in shorts (64 + 8 pad -> 2-way banks only)

typedef __attribute__((ext_vector_type(8))) short  short8;   // 8 bf16 (MFMA A/B frag)
typedef __attribute__((ext_vector_type(4))) float  f32x4;    // MFMA C/D frag

__device__ __forceinline__ unsigned short f2bf(float f) {
    union { float f; unsigned int i; } v; v.f = f;
    unsigned int u = v.i;
    return (unsigned short)((u + 0x7fffu + ((u >> 16) & 1u)) >> 16);  // RNE
}

// ---- 1. histogram of in-degrees -------------------------------------------
__global__ void hist_kernel(const int* __restrict__ ei, int* __restrict__ deg) {
    int e = blockIdx.x * blockDim.x + threadIdx.x;
    if (e < N_EDGES) atomicAdd(&deg[ei[N_EDGES + e]], 1);   // row 1 = dst
}

// ---- 2. exclusive scan (single block, 1024 threads, 10 elems/thread) ------
__global__ void __launch_bounds__(1024) scan_kernel(const int* __restrict__ deg,
                                                    int* __restrict__ offs,
                                                    int* __restrict__ cursor) {
    __shared__ int part[1024];
    int t = threadIdx.x;
    int base = t * 10;
    int local[10];
    int s = 0;
    for (int i = 0; i < 10; ++i) {
        int idx = base + i;
        int d = (idx < N_NODES) ? deg[idx] : 0;
        local[i] = d; s += d;
    }
    part[t] = s;
    __syncthreads();
    for (int o = 1; o < 1024; o <<= 1) {
        int add = (t >= o) ? part[t - o] : 0;
        __syncthreads();
        part[t] += add;
        __syncthreads();
    }
    int run = part[t] - s;
    for (int i = 0; i < 10; ++i) {
        int idx = base + i;
        if (idx < N_NODES) { offs[idx] = run; cursor[idx] = run; run += local[i]; }
    }
    if (t == 1023) offs[N_NODES] = part[1023];
}

// ---- 3. bucket edge ids into CSR ------------------------------------------
__global__ void bucket_kernel(const int* __restrict__ ei, int* __restrict__ cursor,
                              int* __restrict__ esorted) {
    int e = blockIdx.x * blockDim.x + threadIdx.x;
    if (e < N_EDGES) {
        int d = ei[N_EDGES + e];
        int slot = atomicAdd(&cursor[d], 1);
        esorted[slot] = e;
    }
}

// ---- 4. per-node aggregate + fused dense: z = agg@W_rel + x@W_root + b ----
__global__ void __launch_bounds__(64) agg_dense_kernel(
    const float* __restrict__ x,
    const int* __restrict__ ei,
    const float* __restrict__ ew,
    const float* __restrict__ wrel,
    const float* __restrict__ wroot,
    const float* __restrict__ bias,
    const int* __restrict__ offs,
    const int* __restrict__ esorted,
    float* __restrict__ out)               // d_out (fp32)
{
    int i = blockIdx.x;
    int lane = threadIdx.x;
    __shared__ float aggL[DIM_IN];
    __shared__ float xL[DIM_IN];

    int beg = offs[i], end = offs[i + 1];
    const float2* xrow_i = (const float2*)(x + (size_t)i * DIM_IN);
    float2 xi = xrow_i[lane];
    float a0 = 0.f, a1 = 0.f;
    for (int p = beg; p < end; ++p) {
        int e = esorted[p];
        int s = ei[e];                     // row 0 = src
        float w = ew[e];
        float2 xv = ((const float2*)(x + (size_t)s * DIM_IN))[lane];
        a0 += w * xv.x;
        a1 += w * xv.y;
    }
    aggL[2 * lane]     = a0;
    aggL[2 * lane + 1] = a1;
    xL[2 * lane]       = xi.x;
    xL[2 * lane + 1]   = xi.y;
    __syncthreads();

    int h = lane;
    float acc = bias[h];
    for (int k = 0; k < DIM_IN; ++k) {
        acc += aggL[k] * wrel[k * DIM_H + h];
        acc += xL[k]   * wroot[k * DIM_H + h];
    }
    out[(size_t)N_NODES * N_NODES + (size_t)i * DIM_H + h] = acc;  // fp32 z
}

// ---- 5. adj = sigmoid(z @ z^T) --------------------------------------------
// Block tile 128x128, 4 waves of 64x64. z panels staged fp32->bf16 via LDS
// with coalesced float4 loads (fixes R4's 64-line-per-instr fragment gather).
__global__ void __launch_bounds__(256) gemm_sig_kernel(float* __restrict__ out)
{
    const float* zf = out + (size_t)N_NODES * N_NODES;
    __shared__ unsigned short sA[128 * SSTR];
    __shared__ unsigned short sB[128 * SSTR];

    int t    = threadIdx.x;
    int lane = t & 63;
    int wave = t >> 6;
    int wm = wave >> 1, wn = wave & 1;
    int i0 = blockIdx.x * 128;
    int j0 = blockIdx.y * 128;
    int l15  = lane & 15;
    int quad = lane >> 4;

    // ---- stage both 128x64 fp32 panels into LDS as bf16 ----
    {
        int r  = t >> 4;                 // 0..15
        int c4 = (t & 15) << 2;          // 0..60 step 4
        #pragma unroll
        for (int pass = 0; pass < 8; ++pass) {
            int row = pass * 16 + r;
            int ga = i0 + row; if (ga >= N_NODES) ga = N_NODES - 1;
            int gb = j0 + row; if (gb >= N_NODES) gb = N_NODES - 1;
            float4 va = *(const float4*)(zf + (size_t)ga * DIM_H + c4);
            float4 vb = *(const float4*)(zf + (size_t)gb * DIM_H + c4);
            ushort4 ha, hb;
            ha.x = f2bf(va.x); ha.y = f2bf(va.y); ha.z = f2bf(va.z); ha.w = f2bf(va.w);
            hb.x = f2bf(vb.x); hb.y = f2bf(vb.y); hb.z = f2bf(vb.z); hb.w = f2bf(vb.w);
            *(ushort4*)(&sA[row * SSTR + c4]) = ha;
            *(ushort4*)(&sB[row * SSTR + c4]) = hb;
        }
    }
    __syncthreads();

    // ---- MFMA: each wave 64x64 = 4x4 frags, K=64 in two K=32 steps ----
    f32x4 acc[4][4];
    #pragma unroll
    for (int a = 0; a < 4; ++a)
        #pragma unroll
        for (int b = 0; b < 4; ++b) acc[a][b] = (f32x4)0.f;

    #pragma unroll
    for (int s = 0; s < 2; ++s) {
        int kb = quad * 8 + s * 32;               // A[m=lane&15][k=quad*8+j]
        short8 af[4], bfr[4];
        #pragma unroll
        for (int mi = 0; mi < 4; ++mi)
            af[mi] = *(const short8*)(&sA[(wm * 64 + mi * 16 + l15) * SSTR + kb]);
        #pragma unroll
        for (int ni = 0; ni < 4; ++ni)
            bfr[ni] = *(const short8*)(&sB[(wn * 64 + ni * 16 + l15) * SSTR + kb]);
        #pragma unroll
        for (int mi = 0; mi < 4; ++mi)
            #pragma unroll
            for (int ni = 0; ni < 4; ++ni)
                acc[mi][ni] = __builtin_amdgcn_mfma_f32_16x16x32_bf16(
                    af[mi], bfr[ni], acc[mi][ni], 0, 0, 0);
    }

    // ---- epilogue: sigmoid + store (C/D: col=lane&15, row=quad*4+reg) ----
    bool full = (i0 + 127 < N_NODES) && (j0 + 127 < N_NODES);
    if (full) {
        #pragma unroll
        for (int mi = 0; mi < 4; ++mi) {
            #pragma unroll
            for (int ni = 0; ni < 4; ++ni) {
                int col = j0 + wn * 64 + ni * 16 + l15;
                #pragma unroll
                for (int r = 0; r < 4; ++r) {
                    int row = i0 + wm * 64 + mi * 16 + quad * 4 + r;
                    float v  = acc[mi][ni][r];
                    float sg = 1.0f / (1.0f + __expf(-v));
                    out[(size_t)row * N_NODES + col] = sg;
                }
            }
        }
    } else {
        #pragma unroll
        for (int mi = 0; mi < 4; ++mi) {
            #pragma unroll
            for (int ni = 0; ni < 4; ++ni) {
                int col = j0 + wn * 64 + ni * 16 + l15;
                #pragma unroll
                for (int r = 0; r < 4; ++r) {
                    int row = i0 + wm * 64 + mi * 16 + quad * 4 + r;
                    if (row < N_NODES && col < N_NODES) {
                        float v  = acc[mi][ni][r];
                        float sg = 1.0f / (1.0f + __expf(-v));
                        out[(size_t)row * N_NODES + col] = sg;
                    }
                }
            }
        }
    }
}

extern "C" void kernel_launch(void* const* d_in, const int* in_sizes, int n_in,
                              void* d_out, int out_size, void* d_ws, size_t ws_size,
                              hipStream_t stream) {
    const float* x     = (const float*)d_in[0];  // [N,128] fp32
    const int*   ei    = (const int*)d_in[1];    // [2,E] int32
    const float* ew    = (const float*)d_in[2];  // [E] fp32
    const float* wrel  = (const float*)d_in[3];  // [128,64] fp32
    const float* wroot = (const float*)d_in[4];  // [128,64] fp32
    const float* bias  = (const float*)d_in[5];  // [64] fp32
    float* out = (float*)d_out;                  // fp32: adj [N*N] then z [N*64]

    // CSR scratch at the FRONT of the adj region (first ~1.4 MB of 400 MB),
    // fully overwritten by gemm_sig afterwards. d_ws unused.
    char* base = (char*)d_out;
    int* esorted = (int*)(base);                 // E ints
    int* deg     = (int*)(base + 1280000);       // N ints
    int* offs    = (int*)(base + 1320000);       // N+1 ints
    int* cursor  = (int*)(base + 1360004);       // N ints

    hipMemsetAsync(deg, 0, N_NODES * sizeof(int), stream);
    hist_kernel<<<(N_EDGES + 255) / 256, 256, 0, stream>>>(ei, deg);
    scan_kernel<<<1, 1024, 0, stream>>>(deg, offs, cursor);
    bucket_kernel<<<(N_EDGES + 255) / 256, 256, 0, stream>>>(ei, cursor, esorted);
    agg_dense_kernel<<<N_NODES, 64, 0, stream>>>(x, ei, ew, wrel, wroot, bias,
                                                 offs, esorted, out);
    dim3 grid((N_NODES + 127) / 128, (N_NODES + 127) / 128);
    gemm_sig_kernel<<<grid, 256, 0, stream>>>(out);
}